// Round 10
// baseline (1846.403 us; speedup 1.0000x reference)
//
#include <hip/hip_runtime.h>
#include <math.h>

#define B_ 64
#define T_ 48
#define H_ 512
#define V_ 32000
#define G_ 2048
#define BH_ (B_*H_)
#define BG_ (B_*G_)
#define NCE_ 208

typedef short short8 __attribute__((ext_vector_type(8)));
typedef float f32x4 __attribute__((ext_vector_type(4)));

__device__ __forceinline__ float sigmoidf_(float x){ return 1.f/(1.f+__expf(-x)); }

__device__ __forceinline__ unsigned short f2bf(float f){
  unsigned u = __float_as_uint(f);
  u += 0x7fffu + ((u>>16)&1u);
  return (unsigned short)(u>>16);
}
__device__ __forceinline__ float bf2f(unsigned short u){
  return __uint_as_float(((unsigned)u)<<16);
}

__device__ __forceinline__ short8 cvt8(const float* g){
  float4 a = *(const float4*)g;
  float4 b = *(const float4*)(g+4);
  short8 v;
  v[0]=(short)f2bf(a.x); v[1]=(short)f2bf(a.y); v[2]=(short)f2bf(a.z); v[3]=(short)f2bf(a.w);
  v[4]=(short)f2bf(b.x); v[5]=(short)f2bf(b.y); v[6]=(short)f2bf(b.z); v[7]=(short)f2bf(b.w);
  return v;
}

// flag lines (u32 indices, 64B-padded): F1 arrivals 0..31, GO 32..63, CEGO 64..271
#define F1_(i)   ((i)*16)
#define GO_(i)   ((32+(i))*16)
#define CEGO_(i) ((64+(i))*16)

// ---------------------------------------------------------------------------
__global__ void init_kernel(unsigned short* h1_0, unsigned short* h2_0, unsigned* flags){
  int i = blockIdx.x*256 + threadIdx.x;   // 32 blocks
  short8 z = {0,0,0,0,0,0,0,0};
  if (i < 4096) ((short8*)h1_0)[i] = z;
  else          ((short8*)h2_0)[i-4096] = z;
  if (i < 4352) flags[i] = 0u;
}

// ---------------------------------------------------------------------------
__global__ void cvt_cat_kernel(const float* __restrict__ s0, int ld0, int off0,
                               const float* __restrict__ s1, int ld1, int off1,
                               unsigned short* __restrict__ dst, int dld, long total8)
{
  int cols8 = dld >> 3;
  for (long i = blockIdx.x*256 + threadIdx.x; i < total8; i += (long)gridDim.x*256){
    int r = (int)(i / cols8);
    int k = (int)(i - (long)r*cols8) * 8;
    short8 v = (k < 512 || !s1) ? cvt8(s0 + (long)r*ld0 + off0 + k)
                                : cvt8(s1 + (long)r*ld1 + off1 + (k-512));
    *(short8*)(dst + (long)r*dld + k) = v;
  }
}

__global__ void bias_sum_kernel(const float* a1, const float* a2, float* o1,
                                const float* b1, const float* b2, float* o2){
  int n = blockIdx.x*256 + threadIdx.x;
  if (n < G_){ o1[n] = a1[n] + a2[n]; o2[n] = b1[n] + b2[n]; }
}

// ---------------------------------------------------------------------------
// mm_pre: out[s] = bf16( A_slice(s) @ Wbf.T + bA + bB )   (out bf16 now)
// ---------------------------------------------------------------------------
__global__ __launch_bounds__(512,1) void mm_pre_kernel(
    const float* __restrict__ A, int a_bstride,
    const unsigned short* __restrict__ Wbf,
    const float* __restrict__ bA, const float* __restrict__ bB,
    unsigned short* __restrict__ out)
{
  const int s = blockIdx.x, n0 = blockIdx.y*256;
  const int t = threadIdx.x, w = t>>6, l = t&63, ln = l&15, lk = l>>4;
  __shared__ short8 smA[64*64];
  __shared__ short8 smB[256*8];

  const float* af32 = A + (long)s*H_;

  f32x4 acc[4][2];
#pragma unroll
  for (int mf=0; mf<4; ++mf)
#pragma unroll
    for (int nf=0; nf<2; ++nf) acc[mf][nf] = (f32x4){0.f,0.f,0.f,0.f};

#pragma unroll
  for (int i=0;i<8;++i){ int e=i*4096+t*8; int m=e>>9, k=e&511;
    smA[m*64 + ((k>>3)^(m&7))] = cvt8(&af32[(long)m*a_bstride + k]); }

  for (int kc=0; kc<8; ++kc){
    __syncthreads();
#pragma unroll
    for (int i=0;i<4;++i){ int e=i*4096+t*8; int n=e>>6, k=e&63;
      smB[n*8 + ((k>>3)^(n&7))] = *(const short8*)(Wbf + (long)(n0+n)*512 + kc*64 + k); }
    __syncthreads();
#pragma unroll
    for (int ks2=0; ks2<2; ++ks2){
#pragma unroll
      for (int nf=0; nf<2; ++nf){
        int n = w*32 + nf*16 + ln;
        short8 bfr = smB[n*8 + ((ks2*4+lk)^(n&7))];
#pragma unroll
        for (int mf=0; mf<4; ++mf){
          int m = mf*16+ln;
          short8 afr = smA[m*64 + (((kc*2+ks2)*4+lk)^(m&7))];
          acc[mf][nf] = __builtin_amdgcn_mfma_f32_16x16x32_bf16(afr, bfr, acc[mf][nf], 0,0,0);
        }
      }
    }
  }
#pragma unroll
  for (int nf=0; nf<2; ++nf){
    int n = n0 + w*32 + nf*16 + ln;
    float bias = bA[n] + bB[n];
#pragma unroll
    for (int mf=0; mf<4; ++mf)
#pragma unroll
      for (int r=0; r<4; ++r){
        int m = mf*16 + lk*4 + r;
        out[(long)s*BG_ + (long)m*G_ + n] = f2bf(acc[mf][nf][r] + bias);
      }
  }
}

// ---------------------------------------------------------------------------
// mega_kernel: 240 blocks. Blocks 0..31 = merged two-layer chain (single
// barrier domain, both layers per step). Blocks 32..239 = CE consumers,
// gated on private CEGO lines published by the chain master each step.
// h exchange: relaxed agent u64 atomic stores; __syncthreads drains vmcnt
// before arrival flags (validated r5-r9). All flag traffic contention-free.
// ---------------------------------------------------------------------------
__global__ __launch_bounds__(256,1) void mega_kernel(
    const unsigned short* __restrict__ w1e, const unsigned short* __restrict__ w1d, // [2048][512]
    const unsigned short* __restrict__ w2e, const unsigned short* __restrict__ w2d, // [2048][1024]
    const unsigned short* __restrict__ x1b,   // [48][64][2048] bf16
    const unsigned short* __restrict__ capqb, // [47][64][2048] bf16
    const float* __restrict__ bd1s, const float* __restrict__ b2es,
    unsigned short* __restrict__ h1, unsigned short* __restrict__ h2,  // [96][64][512]
    const float* __restrict__ w_o, const float* __restrict__ b_o, const int* __restrict__ ids,
    float* __restrict__ partial, float* __restrict__ tgt,
    unsigned* __restrict__ flags)
{
  __shared__ short8 smA[64*128];        // 128 KB
  __shared__ float gbuf[4][16][68];     // 17 KB (CE: smB region)
  __shared__ float c1_lds[16][68];      // 4.3 KB (CE: red region)
  __shared__ float c2_lds[16][68];      // 4.3 KB (CE: tid_s region)
  const int bc = blockIdx.x;
  const int t = threadIdx.x;
  const int wv = t>>6, l = t&63, ln = l&15, lk = l>>4;

  if (bc < 32){
    // ===================== merged chain =====================
    const int cb = bc;
    unsigned short* stash = (unsigned short*)&smA[0];
    short8 W1e_[16], W1d_[16], W2_[32];              // 256 VGPRs
    const int col = wv*512 + cb*16 + ln;
    {
      const long wr1 = (long)col * 512;
#pragma unroll
      for (int ks=0; ks<16; ++ks){
        W1e_[ks] = *(const short8*)(w1e + wr1 + ks*32 + lk*8);
        W1d_[ks] = *(const short8*)(w1d + wr1 + ks*32 + lk*8);
      }
      const long wr2 = (long)col * 1024;
#pragma unroll
      for (int ks=0; ks<32; ++ks)
        W2_[ks] = *(const short8*)(w2e + wr2 + ks*32 + lk*8);
    }
    const float b1d = bd1s[col], b2e = b2es[col];

    for (int i=t; i<16*68; i+=256){ (&c1_lds[0][0])[i] = 0.f; (&c2_lds[0][0])[i] = 0.f; }
    __syncthreads();

    for (int u=0; u<96; ++u){
      if (u == 49){
        const long wr2 = (long)col * 1024;
#pragma unroll
        for (int ks=0; ks<32; ++ks)
          W2_[ks] = *(const short8*)(w2d + wr2 + ks*32 + lk*8);
      }
      const int L1a = (u<=94), L2a = (u>=1);

      // prev prefetch (independent of h)
      float prev1[4][4], prev2[4][4];
      if (L1a){
        if (u < 48){
          const unsigned short* pp = x1b + (long)u*BG_ + col;
#pragma unroll
          for (int mf=0;mf<4;++mf)
#pragma unroll
            for (int r=0;r<4;++r) prev1[mf][r] = bf2f(pp[(long)(mf*16+lk*4+r)*G_]);
        } else {
#pragma unroll
          for (int mf=0;mf<4;++mf)
#pragma unroll
            for (int r=0;r<4;++r) prev1[mf][r] = b1d;
        }
      }
      if (L2a){
        if (u-1 < 48){
#pragma unroll
          for (int mf=0;mf<4;++mf)
#pragma unroll
            for (int r=0;r<4;++r) prev2[mf][r] = b2e;
        } else {
          const unsigned short* pp = capqb + (long)(u-1-48)*BG_ + col;
#pragma unroll
          for (int mf=0;mf<4;++mf)
#pragma unroll
            for (int r=0;r<4;++r) prev2[mf][r] = bf2f(pp[(long)(mf*16+lk*4+r)*G_]);
        }
      }

      // stage h1[u] (upper half) and h2[u-1] (lower half)
      { const unsigned short* hpB = h1 + (long)u*BH_;
#pragma unroll
        for (int i=0;i<16;++i){ int e=i*2048+t*8; int m=e>>9, k=e&511;
          smA[m*128 + ((k>>3)^(m&7)) + 64] = *(const short8*)(hpB + m*512 + k); }
        if (L2a){
          const unsigned short* hpA = h2 + (long)(u-1)*BH_;
#pragma unroll
          for (int i=0;i<16;++i){ int e=i*2048+t*8; int m=e>>9, k=e&511;
            smA[m*128 + ((k>>3)^(m&7))] = *(const short8*)(hpA + m*512 + k); }
        }
      }
      __syncthreads();

      // both layers' MFMAs before any LDS reuse
      f32x4 acc1[4], acc2[4];
      if (L1a){
#pragma unroll
        for (int mf=0;mf<4;++mf) acc1[mf] = (f32x4){0.f,0.f,0.f,0.f};
        if (u < 48){
#pragma unroll
          for (int ks=0; ks<16; ++ks)
#pragma unroll
            for (int mf=0; mf<4; ++mf){
              int m = mf*16+ln;
              acc1[mf] = __builtin_amdgcn_mfma_f32_16x16x32_bf16(
                smA[m*128 + 64 + ((ks*4+lk)^(m&7))], W1e_[ks], acc1[mf], 0,0,0);
            }
        } else {
#pragma unroll
          for (int ks=0; ks<16; ++ks)
#pragma unroll
            for (int mf=0; mf<4; ++mf){
              int m = mf*16+ln;
              acc1[mf] = __builtin_amdgcn_mfma_f32_16x16x32_bf16(
                smA[m*128 + 64 + ((ks*4+lk)^(m&7))], W1d_[ks], acc1[mf], 0,0,0);
            }
        }
#pragma unroll
        for (int mf=0;mf<4;++mf)
#pragma unroll
          for (int r=0;r<4;++r) acc1[mf][r] += prev1[mf][r];
      }
      if (L2a){
#pragma unroll
        for (int mf=0;mf<4;++mf) acc2[mf] = (f32x4){0.f,0.f,0.f,0.f};
#pragma unroll
        for (int ks=0; ks<32; ++ks)
#pragma unroll
          for (int mf=0; mf<4; ++mf){
            int m = mf*16+ln;
            acc2[mf] = __builtin_amdgcn_mfma_f32_16x16x32_bf16(
              smA[m*128 + ((ks*4+lk)^(m&7))], W2_[ks], acc2[mf], 0,0,0);
          }
#pragma unroll
        for (int mf=0;mf<4;++mf)
#pragma unroll
          for (int r=0;r<4;++r) acc2[mf][r] += prev2[mf][r];
      }

      // ---- L1 cell ----
      if (L1a){
#pragma unroll
        for (int mf=0;mf<4;++mf) *(f32x4*)&gbuf[wv][ln][mf*16+lk*4] = acc1[mf];
      }
      __syncthreads();
      if (L1a){
        int n = t&15, m0 = (t>>4)*4;
        float4 gi = *(float4*)&gbuf[0][n][m0];
        float4 gf = *(float4*)&gbuf[1][n][m0];
        float4 gg = *(float4*)&gbuf[2][n][m0];
        float4 go = *(float4*)&gbuf[3][n][m0];
        float4 c4 = *(float4*)&c1_lds[n][m0];
        float a_i[4]={gi.x,gi.y,gi.z,gi.w}, a_f[4]={gf.x,gf.y,gf.z,gf.w};
        float a_g[4]={gg.x,gg.y,gg.z,gg.w}, a_o[4]={go.x,go.y,go.z,go.w};
        float ci[4]={c4.x,c4.y,c4.z,c4.w}, cn[4];
#pragma unroll
        for (int j=0;j<4;++j){
          float i_ = sigmoidf_(a_i[j]), f_ = sigmoidf_(a_f[j]), o_ = sigmoidf_(a_o[j]);
          float g_ = tanhf(a_g[j]);
          cn[j] = f_*ci[j] + i_*g_;
          stash[(m0+j)*24 + n] = f2bf(o_*tanhf(cn[j]));
        }
        *(float4*)&c1_lds[n][m0] = make_float4(cn[0],cn[1],cn[2],cn[3]);
      }
      __syncthreads();
      if (L1a){
        unsigned short* ho = h1 + (long)(u+1)*BH_ + cb*16;
        int m = t>>2, q = t&3;
        unsigned long long v = *(const unsigned long long*)&stash[m*24 + q*4];
        __hip_atomic_store((unsigned long long*)(ho + (long)m*512 + q*4), v,
                           __ATOMIC_RELAXED, __HIP_MEMORY_SCOPE_AGENT);
      }
      __syncthreads();   // stash reads done -> safe for L2 reuse

      // ---- L2 cell ----
      if (L2a){
#pragma unroll
        for (int mf=0;mf<4;++mf) *(f32x4*)&gbuf[wv][ln][mf*16+lk*4] = acc2[mf];
      }
      __syncthreads();
      if (L2a){
        int n = t&15, m0 = (t>>4)*4;
        float4 gi = *(float4*)&gbuf[0][n][m0];
        float4 gf = *(float4*)&gbuf[1][n][m0];
        float4 gg = *(float4*)&gbuf[2][n][m0];
        float4 go = *(float4*)&gbuf[3][n][m0];
        float4 c4 = *(float4*)&c2_lds[n][m0];
        float a_i[4]={gi.x,gi.y,gi.z,gi.w}, a_f[4]={gf.x,gf.y,gf.z,gf.w};
        float a_g[4]={gg.x,gg.y,gg.z,gg.w}, a_o[4]={go.x,go.y,go.z,go.w};
        float ci[4]={c4.x,c4.y,c4.z,c4.w}, cn[4];
#pragma unroll
        for (int j=0;j<4;++j){
          float i_ = sigmoidf_(a_i[j]), f_ = sigmoidf_(a_f[j]), o_ = sigmoidf_(a_o[j]);
          float g_ = tanhf(a_g[j]);
          cn[j] = f_*ci[j] + i_*g_;
          stash[(m0+j)*24 + n] = f2bf(o_*tanhf(cn[j]));
        }
        *(float4*)&c2_lds[n][m0] = make_float4(cn[0],cn[1],cn[2],cn[3]);
      }
      __syncthreads();
      if (L2a){
        unsigned short* ho = h2 + (long)u*BH_ + cb*16;
        int m = t>>2, q = t&3;
        unsigned long long v = *(const unsigned long long*)&stash[m*24 + q*4];
        __hip_atomic_store((unsigned long long*)(ho + (long)m*512 + q*4), v,
                           __ATOMIC_RELAXED, __HIP_MEMORY_SCOPE_AGENT);
      }

      // ---- barrier + publish (contention-free) ----
      {
        unsigned g = (unsigned)(u+1);
        __syncthreads();   // drains vmcnt: h stores at coherence point
        if (t == 0)
          __hip_atomic_store(&flags[F1_(cb)], g, __ATOMIC_RELAXED, __HIP_MEMORY_SCOPE_AGENT);
        if (cb == 0){
          if (t < 32)
            while (__hip_atomic_load(&flags[F1_(t)], __ATOMIC_RELAXED, __HIP_MEMORY_SCOPE_AGENT) < g)
              __builtin_amdgcn_s_sleep(1);
          __syncthreads();
          if (t >= 1 && t < 32)
            __hip_atomic_store(&flags[GO_(t)], g, __ATOMIC_RELAXED, __HIP_MEMORY_SCOPE_AGENT);
          else if (t >= 32 && t < 32+NCE_)
            __hip_atomic_store(&flags[CEGO_(t-32)], g, __ATOMIC_RELAXED, __HIP_MEMORY_SCOPE_AGENT);
        } else {
          if (u < 95){
            if (t == 0)
              while (__hip_atomic_load(&flags[GO_(cb)], __ATOMIC_RELAXED, __HIP_MEMORY_SCOPE_AGENT) < g)
                __builtin_amdgcn_s_sleep(1);
          }
          __syncthreads();
        }
      }
    }
  } else {
    // ===================== CE consumers =====================
    const int ceid = bc - 32;
    short8* smB = (short8*)&gbuf[0][0][0];            // 16 KB
    float (*red)[64] = (float(*)[64])&c1_lds[0][0];   // 4x64 f32
    int* tid_s = (int*)&c2_lds[0][0];                 // 64 ints

    for (int g2 = ceid; g2 < 47*250; g2 += NCE_){
      int td = g2 / 250, vt = g2 - td*250, v0 = vt*128;
      if (t == 0){
        unsigned need = (unsigned)(50 + td);
        while (__hip_atomic_load(&flags[CEGO_(ceid)], __ATOMIC_RELAXED, __HIP_MEMORY_SCOPE_AGENT) < need)
          __builtin_amdgcn_s_sleep(8);
      }
      __syncthreads();

      if (t < 64) tid_s[t] = ids[t*T_ + td + 1];
      { const unsigned short* hp = h2 + (long)(49+td)*BH_;
#pragma unroll
        for (int i=0;i<16;++i){ int e=i*2048+t*8; int m=e>>9, k=e&511;
          smA[m*64 + ((k>>3)^(m&7))] = *(const short8*)(hp + m*512 + k); } }

      f32x4 acc[4][2];
#pragma unroll
      for (int mf=0; mf<4; ++mf)
#pragma unroll
        for (int nf=0; nf<2; ++nf) acc[mf][nf] = (f32x4){0.f,0.f,0.f,0.f};

      for (int kc=0; kc<8; ++kc){
        __syncthreads();
#pragma unroll
        for (int i=0;i<4;++i){ int e=i*2048+t*8; int n=e>>6, k=e&63;
          smB[n*8 + ((k>>3)^(n&7))] = cvt8(&w_o[(long)(v0+n)*512 + kc*64 + k]); }
        __syncthreads();
#pragma unroll
        for (int ks2=0; ks2<2; ++ks2){
#pragma unroll
          for (int nf=0; nf<2; ++nf){
            int n = wv*32 + nf*16 + ln;
            short8 bfr = smB[n*8 + ((ks2*4+lk)^(n&7))];
#pragma unroll
            for (int mf=0; mf<4; ++mf){
              int m = mf*16+ln;
              short8 afr = smA[m*64 + (((kc*2+ks2)*4+lk)^(m&7))];
              acc[mf][nf] = __builtin_amdgcn_mfma_f32_16x16x32_bf16(afr, bfr, acc[mf][nf], 0,0,0);
            }
          }
        }
      }

      float se[4][4];
#pragma unroll
      for (int mf=0; mf<4; ++mf)
#pragma unroll
        for (int r=0;r<4;++r) se[mf][r] = 0.f;
#pragma unroll
      for (int nf=0; nf<2; ++nf){
        int ng = v0 + wv*32 + nf*16 + ln;
        float bo = b_o[ng];
#pragma unroll
        for (int mf=0; mf<4; ++mf)
#pragma unroll
          for (int r=0;r<4;++r){
            int m = mf*16 + lk*4 + r;
            float lg = acc[mf][nf][r] + bo;
            se[mf][r] += __expf(lg);
            if (ng == tid_s[m]) tgt[td*64 + m] = lg;
          }
      }
#pragma unroll
      for (int off=1; off<16; off<<=1)
#pragma unroll
        for (int mf=0; mf<4; ++mf)
#pragma unroll
          for (int r=0;r<4;++r) se[mf][r] += __shfl_xor(se[mf][r], off);
      if (ln == 0){
#pragma unroll
        for (int mf=0; mf<4; ++mf)
          *(f32x4*)&red[wv][mf*16 + lk*4] = (f32x4){se[mf][0],se[mf][1],se[mf][2],se[mf][3]};
      }
      __syncthreads();
      if (t < 64){
        float ssum = red[0][t] + red[1][t] + red[2][t] + red[3][t];
        partial[(long)vt*3008 + td*64 + t] = ssum;
      }
      __syncthreads();   // before next tile's smA restage
    }
  }
}

__global__ void ce_combine(const float* __restrict__ partial, const float* __restrict__ tgt,
                           float* __restrict__ ce_row){
  int r = blockIdx.x*256 + threadIdx.x;
  if (r < 3008){
    float s = 0.f;
    for (int i=0;i<250;++i) s += partial[(long)i*3008 + r];
    ce_row[r] = __logf(s) - tgt[r];
  }
}

__global__ void ce_final(const float* __restrict__ ce_row, float* __restrict__ out){
  __shared__ float red[256];
  float s = 0.f;
  for (int i=threadIdx.x; i<3008; i+=256) s += ce_row[i];
  red[threadIdx.x] = s;
  __syncthreads();
  for (int off=128; off>0; off>>=1){
    if (threadIdx.x < off) red[threadIdx.x] += red[threadIdx.x + off];
    __syncthreads();
  }
  if (threadIdx.x == 0) out[0] = red[0] * (1.0f/4096.0f);
}

// ---------------------------------------------------------------------------
extern "C" void kernel_launch(void* const* d_in, const int* in_sizes, int n_in,
                              void* d_out, int out_size, void* d_ws, size_t ws_size,
                              hipStream_t stream)
{
  (void)in_sizes; (void)n_in; (void)out_size; (void)ws_size;
  const float* feat    = (const float*)d_in[0];
  const float* caption = (const float*)d_in[1];
  const int*   ids     = (const int*)d_in[2];
  const float* w_ih1  = (const float*)d_in[3];
  const float* w_hh1  = (const float*)d_in[4];
  const float* b_ih1  = (const float*)d_in[5];
  const float* b_hh1  = (const float*)d_in[6];
  const float* w_ih2  = (const float*)d_in[7];
  const float* w_hh2  = (const float*)d_in[8];
  const float* b_ih2  = (const float*)d_in[9];
  const float* b_hh2  = (const float*)d_in[10];
  const float* w_hhd1 = (const float*)d_in[12];
  const float* b_ihd1 = (const float*)d_in[13];
  const float* b_hhd1 = (const float*)d_in[14];
  const float* w_ihd2 = (const float*)d_in[15];
  const float* w_hhd2 = (const float*)d_in[16];
  const float* b_ihd2 = (const float*)d_in[17];
  const float* b_hhd2 = (const float*)d_in[18];
  const float* w_o    = (const float*)d_in[19];
  const float* b_o    = (const float*)d_in[20];

  char* p = (char*)d_ws;
  unsigned short* h1    = (unsigned short*)p; p += 96L*BH_*2;      // 6.29 MB
  unsigned short* h2    = (unsigned short*)p; p += 96L*BH_*2;      // 6.29 MB
  unsigned short* w1e   = (unsigned short*)p; p += 2048L*512*2;
  unsigned short* w1d   = (unsigned short*)p; p += 2048L*512*2;
  unsigned short* w2e   = (unsigned short*)p; p += 2048L*1024*2;
  unsigned short* w2d   = (unsigned short*)p; p += 2048L*1024*2;
  unsigned short* wx1   = (unsigned short*)p; p += 2048L*512*2;
  unsigned short* wcap  = (unsigned short*)p; p += 2048L*512*2;
  unsigned short* x1b   = (unsigned short*)p; p += 48L*BG_*2;      // 12.6 MB
  unsigned short* capqb = (unsigned short*)p; p += 47L*BG_*2;      // 12.3 MB
  float* bd1s  = (float*)p; p += 2048*4;
  float* b2es  = (float*)p; p += 2048*4;
  float* partial = (float*)p; p += 250L*3008*4;                    // 3.0 MB
  float* tgt   = (float*)p; p += 3008*4;
  float* ce_row= (float*)p; p += 3008*4;
  unsigned* flags = (unsigned*)p; p += 4352*4;

  init_kernel<<<32, 256, 0, stream>>>(h1, h2, flags);

  // weight conversions to bf16 (cat layout for layer-2)
  cvt_cat_kernel<<<256, 256, 0, stream>>>(w_hh1, 512, 0, nullptr, 0, 0, w1e, 512, 2048L*64);
  cvt_cat_kernel<<<256, 256, 0, stream>>>(w_hhd1, 512, 0, nullptr, 0, 0, w1d, 512, 2048L*64);
  cvt_cat_kernel<<<256, 256, 0, stream>>>(w_hh2, 512, 0, w_ih2, 1024, 512, w2e, 1024, 2048L*128);
  cvt_cat_kernel<<<256, 256, 0, stream>>>(w_hhd2, 512, 0, w_ihd2, 1024, 512, w2d, 1024, 2048L*128);
  cvt_cat_kernel<<<256, 256, 0, stream>>>(w_ih1, 512, 0, nullptr, 0, 0, wx1, 512, 2048L*64);
  cvt_cat_kernel<<<256, 256, 0, stream>>>(w_ihd2, 1024, 0, nullptr, 0, 0, wcap, 512, 2048L*64);
  bias_sum_kernel<<<8, 256, 0, stream>>>(b_ihd1, b_hhd1, bd1s, b_ih2, b_hh2, b2es);

  // X1[s] (bf16) and capQ[j] (bf16)
  mm_pre_kernel<<<dim3(48,8), 512, 0, stream>>>(feat, T_*H_, wx1, b_ih1, b_hh1, x1b);
  mm_pre_kernel<<<dim3(47,8), 512, 0, stream>>>(caption, T_*H_, wcap, b_ihd2, b_hhd2, capqb);

  // merged chain + overlapped CE in one launch (240 blocks, 1/CU)
  mega_kernel<<<32+NCE_, 256, 0, stream>>>(
      w1e, w1d, w2e, w2d, x1b, capqb, bd1s, b2es, h1, h2,
      w_o, b_o, ids, partial, tgt, flags);

  ce_combine<<<12, 256, 0, stream>>>(partial, tgt, ce_row);
  ce_final<<<1, 256, 0, stream>>>(ce_row, (float*)d_out);
}

// Round 12
// 1579.723 us; speedup vs baseline: 1.1688x; 1.1688x over previous
//
#include <hip/hip_runtime.h>
#include <math.h>

#define B_ 64
#define T_ 48
#define H_ 512
#define V_ 32000
#define G_ 2048
#define BH_ (B_*H_)
#define BG_ (B_*G_)

typedef short short8 __attribute__((ext_vector_type(8)));
typedef float f32x4 __attribute__((ext_vector_type(4)));

__device__ __forceinline__ float sigmoidf_(float x){ return 1.f/(1.f+__expf(-x)); }

__device__ __forceinline__ unsigned short f2bf(float f){
  unsigned u = __float_as_uint(f);
  u += 0x7fffu + ((u>>16)&1u);
  return (unsigned short)(u>>16);
}
__device__ __forceinline__ float bf2f(unsigned short u){
  return __uint_as_float(((unsigned)u)<<16);
}

__device__ __forceinline__ short8 cvt8(const float* g){
  float4 a = *(const float4*)g;
  float4 b = *(const float4*)(g+4);
  short8 v;
  v[0]=(short)f2bf(a.x); v[1]=(short)f2bf(a.y); v[2]=(short)f2bf(a.z); v[3]=(short)f2bf(a.w);
  v[4]=(short)f2bf(b.x); v[5]=(short)f2bf(b.y); v[6]=(short)f2bf(b.z); v[7]=(short)f2bf(b.w);
  return v;
}

// ---------------------------------------------------------------------------
__global__ void init_kernel(unsigned short* h1_0, unsigned short* h2_0, unsigned* flags){
  int i = blockIdx.x*256 + threadIdx.x;   // 32 blocks
  short8 z = {0,0,0,0,0,0,0,0};
  if (i < 4096) ((short8*)h1_0)[i] = z;
  else          ((short8*)h2_0)[i-4096] = z;
  if (i < 1152) flags[i] = 0u;
}

// ---------------------------------------------------------------------------
__global__ void cvt_cat_kernel(const float* __restrict__ s0, int ld0, int off0,
                               const float* __restrict__ s1, int ld1, int off1,
                               unsigned short* __restrict__ dst, int dld, long total8)
{
  int cols8 = dld >> 3;
  for (long i = blockIdx.x*256 + threadIdx.x; i < total8; i += (long)gridDim.x*256){
    int r = (int)(i / cols8);
    int k = (int)(i - (long)r*cols8) * 8;
    short8 v = (k < 512 || !s1) ? cvt8(s0 + (long)r*ld0 + off0 + k)
                                : cvt8(s1 + (long)r*ld1 + off1 + (k-512));
    *(short8*)(dst + (long)r*dld + k) = v;
  }
}

__global__ void bias_sum_kernel(const float* a1, const float* a2, float* o1,
                                const float* b1, const float* b2, float* o2){
  int n = blockIdx.x*256 + threadIdx.x;
  if (n < G_){ o1[n] = a1[n] + a2[n]; o2[n] = b1[n] + b2[n]; }
}

// ---------------------------------------------------------------------------
// mm_pre: out[s] = bf16( A_slice(s) @ Wbf.T + bA + bB )
// ---------------------------------------------------------------------------
__global__ __launch_bounds__(512,1) void mm_pre_kernel(
    const float* __restrict__ A, int a_bstride,
    const unsigned short* __restrict__ Wbf,
    const float* __restrict__ bA, const float* __restrict__ bB,
    unsigned short* __restrict__ out)
{
  const int s = blockIdx.x, n0 = blockIdx.y*256;
  const int t = threadIdx.x, w = t>>6, l = t&63, ln = l&15, lk = l>>4;
  __shared__ short8 smA[64*64];
  __shared__ short8 smB[256*8];

  const float* af32 = A + (long)s*H_;

  f32x4 acc[4][2];
#pragma unroll
  for (int mf=0; mf<4; ++mf)
#pragma unroll
    for (int nf=0; nf<2; ++nf) acc[mf][nf] = (f32x4){0.f,0.f,0.f,0.f};

#pragma unroll
  for (int i=0;i<8;++i){ int e=i*4096+t*8; int m=e>>9, k=e&511;
    smA[m*64 + ((k>>3)^(m&7))] = cvt8(&af32[(long)m*a_bstride + k]); }

  for (int kc=0; kc<8; ++kc){
    __syncthreads();
#pragma unroll
    for (int i=0;i<4;++i){ int e=i*4096+t*8; int n=e>>6, k=e&63;
      smB[n*8 + ((k>>3)^(n&7))] = *(const short8*)(Wbf + (long)(n0+n)*512 + kc*64 + k); }
    __syncthreads();
#pragma unroll
    for (int ks2=0; ks2<2; ++ks2){
#pragma unroll
      for (int nf=0; nf<2; ++nf){
        int n = w*32 + nf*16 + ln;
        short8 bfr = smB[n*8 + ((ks2*4+lk)^(n&7))];
#pragma unroll
        for (int mf=0; mf<4; ++mf){
          int m = mf*16+ln;
          short8 afr = smA[m*64 + (((kc*2+ks2)*4+lk)^(m&7))];
          acc[mf][nf] = __builtin_amdgcn_mfma_f32_16x16x32_bf16(afr, bfr, acc[mf][nf], 0,0,0);
        }
      }
    }
  }
#pragma unroll
  for (int nf=0; nf<2; ++nf){
    int n = n0 + w*32 + nf*16 + ln;
    float bias = bA[n] + bB[n];
#pragma unroll
    for (int mf=0; mf<4; ++mf)
#pragma unroll
      for (int r=0; r<4; ++r){
        int m = mf*16 + lk*4 + r;
        out[(long)s*BG_ + (long)m*G_ + n] = f2bf(acc[mf][nf][r] + bias);
      }
  }
}

// ---------------------------------------------------------------------------
// fused_chain: EXACT r5 structure (best measured: 1115us). 64 blocks,
// L1 = 0..31, L2 = 32..63 lagging one step in the same loop. Single
// all-to-all fence-free barrier per step: each block stores its own padded
// flag; all 64 lanes poll the 64 lines in parallel. h exchange: relaxed
// agent u64 atomic stores; __syncthreads drains vmcnt pre-flag.
// Only change vs r5: x1/capq are bf16.
// ---------------------------------------------------------------------------
__global__ __launch_bounds__(256,1) void fused_chain_kernel(
    const unsigned short* __restrict__ w1e, const unsigned short* __restrict__ w1d, // [2048][512]
    const unsigned short* __restrict__ w2e, const unsigned short* __restrict__ w2d, // [2048][1024]
    const unsigned short* __restrict__ x1b,   // [48][64][2048] bf16
    const unsigned short* __restrict__ capqb, // [47][64][2048] bf16
    const float* __restrict__ bd1s, const float* __restrict__ b2es,
    unsigned short* __restrict__ h1, unsigned short* __restrict__ h2, // [96][64][512]
    unsigned* __restrict__ flags)
{
  const int bc = blockIdx.x;
  const int isL2 = (bc >= 32);
  const int cb = bc & 31;
  const int t = threadIdx.x;
  const int wv = t>>6, l = t&63, ln = l&15, lk = l>>4;

  __shared__ short8 smA[64*128];        // 128 KB
  __shared__ float gbuf[4][16][68];
  __shared__ float c_lds[16][68];
  unsigned short* stash = (unsigned short*)&smA[0];

  short8 W[32];                          // 128 VGPRs
  const int col = wv*512 + cb*16 + ln;
  if (isL2){
    const long wrow = (long)col * 1024;
#pragma unroll
    for (int ks=0; ks<32; ++ks) W[ks] = *(const short8*)(w2e + wrow + ks*32 + lk*8);
  } else {
    const long wrow = (long)col * 512;
#pragma unroll
    for (int ks=0; ks<16; ++ks){
      W[ks]    = *(const short8*)(w1e + wrow + ks*32 + lk*8);
      W[16+ks] = *(const short8*)(w1d + wrow + ks*32 + lk*8);
    }
  }
  const float bext = isL2 ? b2es[col] : bd1s[col];

  for (int i=t; i<16*68; i+=256) (&c_lds[0][0])[i] = 0.f;

  for (int s=0; s<96; ++s){
    if (isL2 && s == 49){                // enc->dec weight swap for layer-2
      const long wrow = (long)col * 1024;
#pragma unroll
      for (int ks=0; ks<32; ++ks) W[ks] = *(const short8*)(w2d + wrow + ks*32 + lk*8);
    }
    const int active = isL2 ? (s>=1) : (s<95);
    if (active){
      // ---- stage h into LDS ----
      if (!isL2){
        const unsigned short* hp = h1 + (long)s*BH_;
#pragma unroll
        for (int i=0;i<16;++i){ int e=i*2048+t*8; int m=e>>9, k=e&511;
          smA[m*128 + ((k>>3)^(m&7))] = *(const short8*)(hp + m*512 + k); }
      } else {
        const unsigned short* hpA = h2 + (long)(s-1)*BH_;
        const unsigned short* hpB = h1 + (long)s*BH_;
#pragma unroll
        for (int i=0;i<16;++i){ int e=i*2048+t*8; int m=e>>9, k=e&511;
          smA[m*128 + ((k>>3)^(m&7))]      = *(const short8*)(hpA + m*512 + k);
          smA[m*128 + ((k>>3)^(m&7)) + 64] = *(const short8*)(hpB + m*512 + k);
        }
      }

      // ---- prefetch pre/bias values (bf16) ----
      const int dec = isL2 ? ((s-1)>=48) : (s>=48);
      float prev[4][4];
      if (!isL2){
        if (s < 48){
          const unsigned short* pp = x1b + (long)s*BG_ + col;
#pragma unroll
          for (int mf=0;mf<4;++mf)
#pragma unroll
            for (int r=0;r<4;++r) prev[mf][r] = bf2f(pp[(long)(mf*16+lk*4+r)*G_]);
        } else {
#pragma unroll
          for (int mf=0;mf<4;++mf)
#pragma unroll
            for (int r=0;r<4;++r) prev[mf][r] = bext;
        }
      } else {
        int s2 = s-1;
        if (s2 < 48){
#pragma unroll
          for (int mf=0;mf<4;++mf)
#pragma unroll
            for (int r=0;r<4;++r) prev[mf][r] = bext;
        } else {
          const unsigned short* pp = capqb + (long)(s2-48)*BG_ + col;
#pragma unroll
          for (int mf=0;mf<4;++mf)
#pragma unroll
            for (int r=0;r<4;++r) prev[mf][r] = bf2f(pp[(long)(mf*16+lk*4+r)*G_]);
        }
      }
      __syncthreads();

      f32x4 acc[4];
#pragma unroll
      for (int mf=0;mf<4;++mf) acc[mf] = (f32x4){0.f,0.f,0.f,0.f};

      if (isL2){
#pragma unroll
        for (int ks=0; ks<32; ++ks)
#pragma unroll
          for (int mf=0; mf<4; ++mf){
            int m = mf*16+ln;
            acc[mf] = __builtin_amdgcn_mfma_f32_16x16x32_bf16(
              smA[m*128 + ((ks*4+lk)^(m&7))], W[ks], acc[mf], 0,0,0);
          }
      } else if (!dec){
#pragma unroll
        for (int ks=0; ks<16; ++ks)
#pragma unroll
          for (int mf=0; mf<4; ++mf){
            int m = mf*16+ln;
            acc[mf] = __builtin_amdgcn_mfma_f32_16x16x32_bf16(
              smA[m*128 + ((ks*4+lk)^(m&7))], W[ks], acc[mf], 0,0,0);
          }
      } else {
#pragma unroll
        for (int ks=0; ks<16; ++ks)
#pragma unroll
          for (int mf=0; mf<4; ++mf){
            int m = mf*16+ln;
            acc[mf] = __builtin_amdgcn_mfma_f32_16x16x32_bf16(
              smA[m*128 + ((ks*4+lk)^(m&7))], W[16+ks], acc[mf], 0,0,0);
          }
      }

#pragma unroll
      for (int mf=0;mf<4;++mf)
#pragma unroll
        for (int r=0;r<4;++r) acc[mf][r] += prev[mf][r];

#pragma unroll
      for (int mf=0;mf<4;++mf) *(f32x4*)&gbuf[wv][ln][mf*16+lk*4] = acc[mf];
      __syncthreads();

      {
        int n = t&15, m0 = (t>>4)*4;
        float4 gi = *(float4*)&gbuf[0][n][m0];
        float4 gf = *(float4*)&gbuf[1][n][m0];
        float4 gg = *(float4*)&gbuf[2][n][m0];
        float4 go = *(float4*)&gbuf[3][n][m0];
        float4 c4 = *(float4*)&c_lds[n][m0];
        float cn[4];
        float a_i[4]={gi.x,gi.y,gi.z,gi.w}, a_f[4]={gf.x,gf.y,gf.z,gf.w};
        float a_g[4]={gg.x,gg.y,gg.z,gg.w}, a_o[4]={go.x,go.y,go.z,go.w};
        float ci[4]={c4.x,c4.y,c4.z,c4.w};
#pragma unroll
        for (int j=0;j<4;++j){
          float i_ = sigmoidf_(a_i[j]), f_ = sigmoidf_(a_f[j]), o_ = sigmoidf_(a_o[j]);
          float g_ = tanhf(a_g[j]);
          cn[j] = f_*ci[j] + i_*g_;
          stash[(m0+j)*24 + n] = f2bf(o_*tanhf(cn[j]));
        }
        *(float4*)&c_lds[n][m0] = make_float4(cn[0],cn[1],cn[2],cn[3]);
      }
      __syncthreads();
      {
        unsigned short* ho = (isL2 ? (h2 + (long)s*BH_) : (h1 + (long)(s+1)*BH_)) + cb*16;
        int m = t>>2, q = t&3;
        unsigned long long v = *(const unsigned long long*)&stash[m*24 + q*4];
        __hip_atomic_store((unsigned long long*)(ho + (long)m*512 + q*4), v,
                           __ATOMIC_RELAXED, __HIP_MEMORY_SCOPE_AGENT);
      }
    }

    // ---- all-to-all flag barrier (r5-validated) ----
    if (s < 95){
      unsigned g = (unsigned)(s+1);
      __syncthreads();   // drains vmcnt per wave before s_barrier
      if (t == 0)
        __hip_atomic_store(&flags[bc*16], g, __ATOMIC_RELAXED, __HIP_MEMORY_SCOPE_AGENT);
      if (t < 64){
        while (__hip_atomic_load(&flags[t*16], __ATOMIC_RELAXED, __HIP_MEMORY_SCOPE_AGENT) < g)
          __builtin_amdgcn_s_sleep(1);
      }
      __syncthreads();
    }
  }
}

// ---------------------------------------------------------------------------
// ce_vt: one block per 128-vocab slice (250 blocks, 512 thr). w_o slice
// resident in LDS for all 47 decoder steps (47x less w_o traffic).
// ---------------------------------------------------------------------------
__global__ __launch_bounds__(512,1) void ce_vt_kernel(
    const unsigned short* __restrict__ h2_bf, const unsigned short* __restrict__ wo_bf,
    const float* __restrict__ b_o, const int* __restrict__ ids,
    float* __restrict__ partial, float* __restrict__ tgt)
{
  const int vt = blockIdx.x, v0 = vt*128;
  const int t = threadIdx.x, wv = t>>6, l = t&63, ln = l&15, lk = l>>4;
  __shared__ short8 smB[128*64];   // 128 KB: [n][k-chunk] swizzled
  __shared__ short8 smAc[64*8];    // 8 KB per-kc A chunk
  __shared__ float red[8][64];
  __shared__ int tid_s[64];

  // stage w_o slice once (swizzled: low 3 chunk bits ^ (n&7))
  for (int i = t; i < 128*64; i += 512){
    int n = i >> 6, c = i & 63;
    smB[n*64 + ((c & 56) | ((c & 7) ^ (n & 7)))] =
        *(const short8*)(wo_bf + (long)(v0+n)*512 + c*8);
  }
  const int nn = wv*16 + ln;                // this lane's column (0..127)
  const float bo = b_o[v0 + nn];
  __syncthreads();

  for (int td = 0; td < 47; ++td){
    if (t < 64) tid_s[t] = ids[t*T_ + td + 1];
    const unsigned short* hp = h2_bf + (long)(49+td)*BH_;

    f32x4 acc[4];
#pragma unroll
    for (int mf=0;mf<4;++mf) acc[mf] = (f32x4){0.f,0.f,0.f,0.f};

    for (int kc=0; kc<8; ++kc){
      __syncthreads();   // previous kc reads (and prev-td red/tid_s reads) done
      { int m = t>>3, c = t&7;
        smAc[m*8 + (c ^ (m&7))] = *(const short8*)(hp + m*512 + kc*64 + c*8); }
      __syncthreads();
#pragma unroll
      for (int ks2=0; ks2<2; ++ks2){
        short8 bfr = smB[nn*64 + kc*8 + ((ks2*4+lk)^(nn&7))];
#pragma unroll
        for (int mf=0; mf<4; ++mf){
          int m = mf*16+ln;
          short8 afr = smAc[m*8 + ((ks2*4+lk)^(m&7))];
          acc[mf] = __builtin_amdgcn_mfma_f32_16x16x32_bf16(afr, bfr, acc[mf], 0,0,0);
        }
      }
    }

    // logits -> sum-exp (reduce over the wave's 16 columns) + target gather
    float se[4][4];
#pragma unroll
    for (int mf=0; mf<4; ++mf)
#pragma unroll
      for (int r=0;r<4;++r){
        int m = mf*16 + lk*4 + r;
        float lg = acc[mf][r] + bo;
        se[mf][r] = __expf(lg);
        if (v0 + nn == tid_s[m]) tgt[td*64 + m] = lg;
      }
#pragma unroll
    for (int off=1; off<16; off<<=1)
#pragma unroll
      for (int mf=0; mf<4; ++mf)
#pragma unroll
        for (int r=0;r<4;++r) se[mf][r] += __shfl_xor(se[mf][r], off);
    if (ln == 0){
#pragma unroll
      for (int mf=0; mf<4; ++mf)
        *(f32x4*)&red[wv][mf*16 + lk*4] = (f32x4){se[mf][0],se[mf][1],se[mf][2],se[mf][3]};
    }
    __syncthreads();
    if (t < 64){
      float ssum = 0.f;
#pragma unroll
      for (int w2=0; w2<8; ++w2) ssum += red[w2][t];
      partial[(long)vt*3008 + td*64 + t] = ssum;
    }
  }
}

__global__ void ce_combine(const float* __restrict__ partial, const float* __restrict__ tgt,
                           float* __restrict__ ce_row){
  int r = blockIdx.x*256 + threadIdx.x;
  if (r < 3008){
    float s = 0.f;
    for (int i=0;i<250;++i) s += partial[(long)i*3008 + r];
    ce_row[r] = __logf(s) - tgt[r];
  }
}

__global__ void ce_final(const float* __restrict__ ce_row, float* __restrict__ out){
  __shared__ float red[256];
  float s = 0.f;
  for (int i=threadIdx.x; i<3008; i+=256) s += ce_row[i];
  red[threadIdx.x] = s;
  __syncthreads();
  for (int off=128; off>0; off>>=1){
    if (threadIdx.x < off) red[threadIdx.x] += red[threadIdx.x + off];
    __syncthreads();
  }
  if (threadIdx.x == 0) out[0] = red[0] * (1.0f/4096.0f);
}

// ---------------------------------------------------------------------------
extern "C" void kernel_launch(void* const* d_in, const int* in_sizes, int n_in,
                              void* d_out, int out_size, void* d_ws, size_t ws_size,
                              hipStream_t stream)
{
  (void)in_sizes; (void)n_in; (void)out_size; (void)ws_size;
  const float* feat    = (const float*)d_in[0];
  const float* caption = (const float*)d_in[1];
  const int*   ids     = (const int*)d_in[2];
  const float* w_ih1  = (const float*)d_in[3];
  const float* w_hh1  = (const float*)d_in[4];
  const float* b_ih1  = (const float*)d_in[5];
  const float* b_hh1  = (const float*)d_in[6];
  const float* w_ih2  = (const float*)d_in[7];
  const float* w_hh2  = (const float*)d_in[8];
  const float* b_ih2  = (const float*)d_in[9];
  const float* b_hh2  = (const float*)d_in[10];
  const float* w_hhd1 = (const float*)d_in[12];
  const float* b_ihd1 = (const float*)d_in[13];
  const float* b_hhd1 = (const float*)d_in[14];
  const float* w_ihd2 = (const float*)d_in[15];
  const float* w_hhd2 = (const float*)d_in[16];
  const float* b_ihd2 = (const float*)d_in[17];
  const float* b_hhd2 = (const float*)d_in[18];
  const float* w_o    = (const float*)d_in[19];
  const float* b_o    = (const float*)d_in[20];

  char* p = (char*)d_ws;
  unsigned short* h1    = (unsigned short*)p; p += 96L*BH_*2;      // 6.29 MB
  unsigned short* h2    = (unsigned short*)p; p += 96L*BH_*2;      // 6.29 MB
  unsigned short* w2e   = (unsigned short*)p; p += 2048L*1024*2;   // 4.19 MB
  unsigned short* w2d   = (unsigned short*)p; p += 2048L*1024*2;
  // ---- alias region: chain-phase buffers, reused as wo_bf for CE ----
  char* alias0 = p;
  unsigned short* w1e   = (unsigned short*)p; p += 2048L*512*2;    // 2.10 MB
  unsigned short* w1d   = (unsigned short*)p; p += 2048L*512*2;
  unsigned short* wx1   = (unsigned short*)p; p += 2048L*512*2;
  unsigned short* wcap  = (unsigned short*)p; p += 2048L*512*2;
  unsigned short* x1b   = (unsigned short*)p; p += 48L*BG_*2;      // 12.6 MB
  unsigned short* capqb = (unsigned short*)p; p += 47L*BG_*2;      // 12.3 MB -> 33.35 MB total
  unsigned short* wo_bf = (unsigned short*)alias0;                 // 32.8 MB (CE phase only)
  float* bd1s  = (float*)p; p += 2048*4;
  float* b2es  = (float*)p; p += 2048*4;
  float* partial = (float*)p; p += 250L*3008*4;                    // 3.0 MB
  float* tgt   = (float*)p; p += 3008*4;
  float* ce_row= (float*)p; p += 3008*4;
  unsigned* flags = (unsigned*)p; p += 1152*4;

  init_kernel<<<32, 256, 0, stream>>>(h1, h2, flags);

  // weight conversions to bf16 (cat layout for layer-2)
  cvt_cat_kernel<<<256, 256, 0, stream>>>(w_hh1, 512, 0, nullptr, 0, 0, w1e, 512, 2048L*64);
  cvt_cat_kernel<<<256, 256, 0, stream>>>(w_hhd1, 512, 0, nullptr, 0, 0, w1d, 512, 2048L*64);
  cvt_cat_kernel<<<256, 256, 0, stream>>>(w_hh2, 512, 0, w_ih2, 1024, 512, w2e, 1024, 2048L*128);
  cvt_cat_kernel<<<256, 256, 0, stream>>>(w_hhd2, 512, 0, w_ihd2, 1024, 512, w2d, 1024, 2048L*128);
  cvt_cat_kernel<<<256, 256, 0, stream>>>(w_ih1, 512, 0, nullptr, 0, 0, wx1, 512, 2048L*64);
  cvt_cat_kernel<<<256, 256, 0, stream>>>(w_ihd2, 1024, 0, nullptr, 0, 0, wcap, 512, 2048L*64);
  bias_sum_kernel<<<8, 256, 0, stream>>>(b_ihd1, b_hhd1, bd1s, b_ih2, b_hh2, b2es);

  // X1[s] (bf16) and capQ[j] (bf16)
  mm_pre_kernel<<<dim3(48,8), 512, 0, stream>>>(feat, T_*H_, wx1, b_ih1, b_hh1, x1b);
  mm_pre_kernel<<<dim3(47,8), 512, 0, stream>>>(caption, T_*H_, wcap, b_ihd2, b_hhd2, capqb);

  // fused two-layer chain (r5 structure, best measured)
  fused_chain_kernel<<<64, 256, 0, stream>>>(w1e, w1d, w2e, w2d, x1b, capqb, bd1s, b2es, h1, h2, flags);

  // w_o -> bf16 into the now-dead alias region
  cvt_cat_kernel<<<512, 256, 0, stream>>>(w_o, 512, 0, nullptr, 0, 0, wo_bf, 512, 32000L*64);

  // CE with LDS-resident w_o slice per block
  ce_vt_kernel<<<250, 512, 0, stream>>>(h2, wo_bf, b_o, ids, partial, tgt);
  ce_combine<<<12, 256, 0, stream>>>(partial, tgt, ce_row);
  ce_final<<<1, 256, 0, stream>>>(ce_row, (float*)d_out);
}

// Round 13
// 1536.792 us; speedup vs baseline: 1.2015x; 1.0279x over previous
//
#include <hip/hip_runtime.h>
#include <math.h>

#define B_ 64
#define T_ 48
#define H_ 512
#define V_ 32000
#define G_ 2048
#define BH_ (B_*H_)
#define BG_ (B_*G_)
#define NCE_ 186

typedef short short8 __attribute__((ext_vector_type(8)));
typedef float f32x4 __attribute__((ext_vector_type(4)));

__device__ __forceinline__ float sigmoidf_(float x){ return 1.f/(1.f+__expf(-x)); }

__device__ __forceinline__ unsigned short f2bf(float f){
  unsigned u = __float_as_uint(f);
  u += 0x7fffu + ((u>>16)&1u);
  return (unsigned short)(u>>16);
}
__device__ __forceinline__ float bf2f(unsigned short u){
  return __uint_as_float(((unsigned)u)<<16);
}

__device__ __forceinline__ short8 cvt8(const float* g){
  float4 a = *(const float4*)g;
  float4 b = *(const float4*)(g+4);
  short8 v;
  v[0]=(short)f2bf(a.x); v[1]=(short)f2bf(a.y); v[2]=(short)f2bf(a.z); v[3]=(short)f2bf(a.w);
  v[4]=(short)f2bf(b.x); v[5]=(short)f2bf(b.y); v[6]=(short)f2bf(b.z); v[7]=(short)f2bf(b.w);
  return v;
}

// flag lines (u32 idx, 64B-padded): chain flags 0..1023 (bc*16), CEGO (64+i)*16
#define CEGO_(i) ((64+(i))*16)

// ---------------------------------------------------------------------------
// prep: all weight conversions + bias sums + state/flag init, one launch
// ---------------------------------------------------------------------------
__global__ void prep_kernel(
    const float* __restrict__ w_hh1, const float* __restrict__ w_hhd1,
    const float* __restrict__ w_hh2, const float* __restrict__ w_ih2,
    const float* __restrict__ w_hhd2, const float* __restrict__ w_ihd2,
    const float* __restrict__ w_ih1, const float* __restrict__ w_o,
    const float* __restrict__ b_ihd1, const float* __restrict__ b_hhd1,
    const float* __restrict__ b_ih2,  const float* __restrict__ b_hh2,
    unsigned short* w1e, unsigned short* w1d, unsigned short* w2e, unsigned short* w2d,
    unsigned short* wx1, unsigned short* wcap, unsigned short* wo_bf,
    float* bd1s, float* b2es,
    unsigned short* h1_0, unsigned short* h2_0, unsigned* flags)
{
  const int b = blockIdx.x, t = threadIdx.x;
  if (b < 64){
    for (long i = b*256+t; i < 2048L*64; i += 64L*256){ int r=(int)(i>>6), k=(int)(i&63)*8;
      *(short8*)(w1e + (long)r*512 + k) = cvt8(w_hh1 + (long)r*512 + k); }
  } else if (b < 128){
    for (long i = (b-64)*256+t; i < 2048L*64; i += 64L*256){ int r=(int)(i>>6), k=(int)(i&63)*8;
      *(short8*)(w1d + (long)r*512 + k) = cvt8(w_hhd1 + (long)r*512 + k); }
  } else if (b < 256){
    for (long i = (b-128)*256+t; i < 2048L*128; i += 128L*256){ int r=(int)(i>>7), k=(int)(i&127)*8;
      short8 v = (k<512)? cvt8(w_hh2+(long)r*512+k) : cvt8(w_ih2+(long)r*1024+512+(k-512));
      *(short8*)(w2e + (long)r*1024 + k) = v; }
  } else if (b < 384){
    for (long i = (b-256)*256+t; i < 2048L*128; i += 128L*256){ int r=(int)(i>>7), k=(int)(i&127)*8;
      short8 v = (k<512)? cvt8(w_hhd2+(long)r*512+k) : cvt8(w_ihd2+(long)r*1024+512+(k-512));
      *(short8*)(w2d + (long)r*1024 + k) = v; }
  } else if (b < 448){
    for (long i = (b-384)*256+t; i < 2048L*64; i += 64L*256){ int r=(int)(i>>6), k=(int)(i&63)*8;
      *(short8*)(wx1 + (long)r*512 + k) = cvt8(w_ih1 + (long)r*512 + k); }
  } else if (b < 512){
    for (long i = (b-448)*256+t; i < 2048L*64; i += 64L*256){ int r=(int)(i>>6), k=(int)(i&63)*8;
      *(short8*)(wcap + (long)r*512 + k) = cvt8(w_ihd2 + (long)r*1024 + k); }
  } else if (b < 1012){
    for (long i = (long)(b-512)*256+t; i < 32000L*64; i += 500L*256){ int r=(int)(i>>6), k=(int)(i&63)*8;
      *(short8*)(wo_bf + (long)r*512 + k) = cvt8(w_o + (long)r*512 + k); }
  } else if (b < 1020){
    int n = (b-1012)*256 + t;
    bd1s[n] = b_ihd1[n] + b_hhd1[n];
    b2es[n] = b_ih2[n] + b_hh2[n];
  } else {
    short8 z = {0,0,0,0,0,0,0,0};
    for (int i=(b-1020)*256+t; i<4096; i+=4*256){ ((short8*)h1_0)[i]=z; ((short8*)h2_0)[i]=z; }
    for (int i=(b-1020)*256+t; i<4096; i+=4*256) flags[i] = 0u;
  }
}

// ---------------------------------------------------------------------------
// mm_pre2: fused X1 (s<48, from feat) and capQ (s>=48, from caption), bf16 out
// ---------------------------------------------------------------------------
__global__ __launch_bounds__(512,1) void mm_pre2_kernel(
    const float* __restrict__ feat, const float* __restrict__ caption,
    const unsigned short* __restrict__ wx1, const unsigned short* __restrict__ wcap,
    const float* __restrict__ b_ih1, const float* __restrict__ b_hh1,
    const float* __restrict__ b_ihd2, const float* __restrict__ b_hhd2,
    unsigned short* __restrict__ x1b, unsigned short* __restrict__ capqb)
{
  const int s = blockIdx.x, n0 = blockIdx.y*256;
  const int t = threadIdx.x, w = t>>6, l = t&63, ln = l&15, lk = l>>4;
  __shared__ short8 smA[64*64];
  __shared__ short8 smB[256*8];

  const float* af32; const unsigned short* Wbf; const float* bA; const float* bB;
  unsigned short* out;
  if (s < 48){ af32 = feat + (long)s*H_;          Wbf = wx1;  bA = b_ih1;  bB = b_hh1;  out = x1b  + (long)s*BG_; }
  else       { af32 = caption + (long)(s-48)*H_;  Wbf = wcap; bA = b_ihd2; bB = b_hhd2; out = capqb + (long)(s-48)*BG_; }

  f32x4 acc[4][2];
#pragma unroll
  for (int mf=0; mf<4; ++mf)
#pragma unroll
    for (int nf=0; nf<2; ++nf) acc[mf][nf] = (f32x4){0.f,0.f,0.f,0.f};

#pragma unroll
  for (int i=0;i<8;++i){ int e=i*4096+t*8; int m=e>>9, k=e&511;
    smA[m*64 + ((k>>3)^(m&7))] = cvt8(&af32[(long)m*(T_*H_) + k]); }

  for (int kc=0; kc<8; ++kc){
    __syncthreads();
#pragma unroll
    for (int i=0;i<4;++i){ int e=i*4096+t*8; int n=e>>6, k=e&63;
      smB[n*8 + ((k>>3)^(n&7))] = *(const short8*)(Wbf + (long)(n0+n)*512 + kc*64 + k); }
    __syncthreads();
#pragma unroll
    for (int ks2=0; ks2<2; ++ks2){
#pragma unroll
      for (int nf=0; nf<2; ++nf){
        int n = w*32 + nf*16 + ln;
        short8 bfr = smB[n*8 + ((ks2*4+lk)^(n&7))];
#pragma unroll
        for (int mf=0; mf<4; ++mf){
          int m = mf*16+ln;
          short8 afr = smA[m*64 + (((kc*2+ks2)*4+lk)^(m&7))];
          acc[mf][nf] = __builtin_amdgcn_mfma_f32_16x16x32_bf16(afr, bfr, acc[mf][nf], 0,0,0);
        }
      }
    }
  }
#pragma unroll
  for (int nf=0; nf<2; ++nf){
    int n = n0 + w*32 + nf*16 + ln;
    float bias = bA[n] + bB[n];
#pragma unroll
    for (int mf=0; mf<4; ++mf)
#pragma unroll
      for (int r=0; r<4; ++r){
        int m = mf*16 + lk*4 + r;
        out[(long)m*G_ + n] = f2bf(acc[mf][nf][r] + bias);
      }
  }
}

// ---------------------------------------------------------------------------
// mega: blocks 0..63 = r12 chain (verbatim + CEGO publish + final g=96);
// blocks 64..249 = CE consumers (LDS-resident bf16 w_o slice, private gating).
// ---------------------------------------------------------------------------
__global__ __launch_bounds__(256,1) void mega_kernel(
    const unsigned short* __restrict__ w1e, const unsigned short* __restrict__ w1d,
    const unsigned short* __restrict__ w2e, const unsigned short* __restrict__ w2d,
    const unsigned short* __restrict__ x1b, const unsigned short* __restrict__ capqb,
    const float* __restrict__ bd1s, const float* __restrict__ b2es,
    unsigned short* __restrict__ h1, unsigned short* __restrict__ h2,
    const unsigned short* __restrict__ wo_bf, const float* __restrict__ b_o,
    const int* __restrict__ ids,
    float* __restrict__ partial, float* __restrict__ tgt,
    unsigned* __restrict__ flags)
{
  __shared__ short8 smA[64*128];        // 128 KB
  __shared__ float gbuf[4][16][68];     // 17.4 KB
  __shared__ float c_lds[16][68];       // 4.35 KB
  const int bcg = blockIdx.x;
  const int t = threadIdx.x;
  const int wv = t>>6, l = t&63, ln = l&15, lk = l>>4;

  if (bcg < 64){
    // ======================= chain (r12 structure) =======================
    const int bc = bcg;
    const int isL2 = (bc >= 32);
    const int cb = bc & 31;
    unsigned short* stash = (unsigned short*)&smA[0];

    short8 W[32];
    const int col = wv*512 + cb*16 + ln;
    if (isL2){
      const long wrow = (long)col * 1024;
#pragma unroll
      for (int ks=0; ks<32; ++ks) W[ks] = *(const short8*)(w2e + wrow + ks*32 + lk*8);
    } else {
      const long wrow = (long)col * 512;
#pragma unroll
      for (int ks=0; ks<16; ++ks){
        W[ks]    = *(const short8*)(w1e + wrow + ks*32 + lk*8);
        W[16+ks] = *(const short8*)(w1d + wrow + ks*32 + lk*8);
      }
    }
    const float bext = isL2 ? b2es[col] : bd1s[col];

    for (int i=t; i<16*68; i+=256) (&c_lds[0][0])[i] = 0.f;

    for (int s=0; s<96; ++s){
      if (isL2 && s == 49){
        const long wrow = (long)col * 1024;
#pragma unroll
        for (int ks=0; ks<32; ++ks) W[ks] = *(const short8*)(w2d + wrow + ks*32 + lk*8);
      }
      const int active = isL2 ? (s>=1) : (s<95);
      if (active){
        if (!isL2){
          const unsigned short* hp = h1 + (long)s*BH_;
#pragma unroll
          for (int i=0;i<16;++i){ int e=i*2048+t*8; int m=e>>9, k=e&511;
            smA[m*128 + ((k>>3)^(m&7))] = *(const short8*)(hp + m*512 + k); }
        } else {
          const unsigned short* hpA = h2 + (long)(s-1)*BH_;
          const unsigned short* hpB = h1 + (long)s*BH_;
#pragma unroll
          for (int i=0;i<16;++i){ int e=i*2048+t*8; int m=e>>9, k=e&511;
            smA[m*128 + ((k>>3)^(m&7))]      = *(const short8*)(hpA + m*512 + k);
            smA[m*128 + ((k>>3)^(m&7)) + 64] = *(const short8*)(hpB + m*512 + k);
          }
        }

        const int dec = isL2 ? ((s-1)>=48) : (s>=48);
        float prev[4][4];
        if (!isL2){
          if (s < 48){
            const unsigned short* pp = x1b + (long)s*BG_ + col;
#pragma unroll
            for (int mf=0;mf<4;++mf)
#pragma unroll
              for (int r=0;r<4;++r) prev[mf][r] = bf2f(pp[(long)(mf*16+lk*4+r)*G_]);
          } else {
#pragma unroll
            for (int mf=0;mf<4;++mf)
#pragma unroll
              for (int r=0;r<4;++r) prev[mf][r] = bext;
          }
        } else {
          int s2 = s-1;
          if (s2 < 48){
#pragma unroll
            for (int mf=0;mf<4;++mf)
#pragma unroll
              for (int r=0;r<4;++r) prev[mf][r] = bext;
          } else {
            const unsigned short* pp = capqb + (long)(s2-48)*BG_ + col;
#pragma unroll
            for (int mf=0;mf<4;++mf)
#pragma unroll
              for (int r=0;r<4;++r) prev[mf][r] = bf2f(pp[(long)(mf*16+lk*4+r)*G_]);
          }
        }
        __syncthreads();

        f32x4 acc[4];
#pragma unroll
        for (int mf=0;mf<4;++mf) acc[mf] = (f32x4){0.f,0.f,0.f,0.f};

        if (isL2){
#pragma unroll
          for (int ks=0; ks<32; ++ks)
#pragma unroll
            for (int mf=0; mf<4; ++mf){
              int m = mf*16+ln;
              acc[mf] = __builtin_amdgcn_mfma_f32_16x16x32_bf16(
                smA[m*128 + ((ks*4+lk)^(m&7))], W[ks], acc[mf], 0,0,0);
            }
        } else if (!dec){
#pragma unroll
          for (int ks=0; ks<16; ++ks)
#pragma unroll
            for (int mf=0; mf<4; ++mf){
              int m = mf*16+ln;
              acc[mf] = __builtin_amdgcn_mfma_f32_16x16x32_bf16(
                smA[m*128 + ((ks*4+lk)^(m&7))], W[ks], acc[mf], 0,0,0);
            }
        } else {
#pragma unroll
          for (int ks=0; ks<16; ++ks)
#pragma unroll
            for (int mf=0; mf<4; ++mf){
              int m = mf*16+ln;
              acc[mf] = __builtin_amdgcn_mfma_f32_16x16x32_bf16(
                smA[m*128 + ((ks*4+lk)^(m&7))], W[16+ks], acc[mf], 0,0,0);
            }
        }

#pragma unroll
        for (int mf=0;mf<4;++mf)
#pragma unroll
          for (int r=0;r<4;++r) acc[mf][r] += prev[mf][r];

#pragma unroll
        for (int mf=0;mf<4;++mf) *(f32x4*)&gbuf[wv][ln][mf*16+lk*4] = acc[mf];
        __syncthreads();

        {
          int n = t&15, m0 = (t>>4)*4;
          float4 gi = *(float4*)&gbuf[0][n][m0];
          float4 gf = *(float4*)&gbuf[1][n][m0];
          float4 gg = *(float4*)&gbuf[2][n][m0];
          float4 go = *(float4*)&gbuf[3][n][m0];
          float4 c4 = *(float4*)&c_lds[n][m0];
          float cn[4];
          float a_i[4]={gi.x,gi.y,gi.z,gi.w}, a_f[4]={gf.x,gf.y,gf.z,gf.w};
          float a_g[4]={gg.x,gg.y,gg.z,gg.w}, a_o[4]={go.x,go.y,go.z,go.w};
          float ci[4]={c4.x,c4.y,c4.z,c4.w};
#pragma unroll
          for (int j=0;j<4;++j){
            float i_ = sigmoidf_(a_i[j]), f_ = sigmoidf_(a_f[j]), o_ = sigmoidf_(a_o[j]);
            float g_ = tanhf(a_g[j]);
            cn[j] = f_*ci[j] + i_*g_;
            stash[(m0+j)*24 + n] = f2bf(o_*tanhf(cn[j]));
          }
          *(float4*)&c_lds[n][m0] = make_float4(cn[0],cn[1],cn[2],cn[3]);
        }
        __syncthreads();
        {
          unsigned short* ho = (isL2 ? (h2 + (long)s*BH_) : (h1 + (long)(s+1)*BH_)) + cb*16;
          int m = t>>2, q = t&3;
          unsigned long long v = *(const unsigned long long*)&stash[m*24 + q*4];
          __hip_atomic_store((unsigned long long*)(ho + (long)m*512 + q*4), v,
                             __ATOMIC_RELAXED, __HIP_MEMORY_SCOPE_AGENT);
        }
      }

      if (s < 95){
        unsigned g = (unsigned)(s+1);
        __syncthreads();   // drains vmcnt per wave before s_barrier
        if (t == 0)
          __hip_atomic_store(&flags[bcg*16], g, __ATOMIC_RELAXED, __HIP_MEMORY_SCOPE_AGENT);
        if (t < 64){
          while (__hip_atomic_load(&flags[t*16], __ATOMIC_RELAXED, __HIP_MEMORY_SCOPE_AGENT) < g)
            __builtin_amdgcn_s_sleep(1);
        }
        __syncthreads();
        if (bcg == 32 && g >= 50 && t < NCE_)
          __hip_atomic_store(&flags[CEGO_(t)], g, __ATOMIC_RELAXED, __HIP_MEMORY_SCOPE_AGENT);
      }
    }
    // final signal: h2[95] complete -> g=96
    __syncthreads();   // drain vmcnt for s=95 stores
    if (t == 0)
      __hip_atomic_store(&flags[bcg*16], 96u, __ATOMIC_RELAXED, __HIP_MEMORY_SCOPE_AGENT);
    if (bcg == 32){
      if (t >= 32 && t < 64){
        while (__hip_atomic_load(&flags[t*16], __ATOMIC_RELAXED, __HIP_MEMORY_SCOPE_AGENT) < 96u)
          __builtin_amdgcn_s_sleep(1);
      }
      __syncthreads();
      if (t < NCE_)
        __hip_atomic_store(&flags[CEGO_(t)], 96u, __ATOMIC_RELAXED, __HIP_MEMORY_SCOPE_AGENT);
    }
  } else {
    // ======================= CE consumers =======================
    const int ceid = bcg - 64;
    short8* smB  = smA;                         // 128 KB w_o slice
    short8* smAc = (short8*)&gbuf[0][0][0];     // 8 KB A chunk
    float*  redf = &c_lds[0][0];                // 4x64 floats
    int*    tid_s = (int*)(&c_lds[0][0]) + 256; // 64 ints

    for (int slice = ceid; slice < 250; slice += NCE_){
      const int vt = slice, v0 = vt*128;
      __syncthreads();   // prior slice reads done before smB restage
      for (int i = t; i < 128*64; i += 256){
        int n = i >> 6, c = i & 63;
        smB[n*64 + ((c & 56) | ((c & 7) ^ (n & 7)))] =
            *(const short8*)(wo_bf + (long)(v0+n)*512 + c*8);
      }

      for (int td = 0; td < 47; ++td){
        if (t == 0){
          unsigned need = (unsigned)(50 + td);
          while (__hip_atomic_load(&flags[CEGO_(ceid)], __ATOMIC_RELAXED, __HIP_MEMORY_SCOPE_AGENT) < need)
            __builtin_amdgcn_s_sleep(8);
        }
        if (t < 64) tid_s[t] = ids[t*T_ + td + 1];
        const unsigned short* hp = h2 + (long)(49+td)*BH_;

        f32x4 acc[4][2];
#pragma unroll
        for (int mf=0; mf<4; ++mf)
#pragma unroll
          for (int nf=0; nf<2; ++nf) acc[mf][nf] = (f32x4){0.f,0.f,0.f,0.f};

        for (int kc=0; kc<8; ++kc){
          __syncthreads();   // gate+tid_s visible; prior kc reads done
#pragma unroll
          for (int i=0;i<2;++i){ int e=i*256+t; int m=e>>3, c=e&7;
            smAc[m*8 + (c ^ (m&7))] = *(const short8*)(hp + m*512 + kc*64 + c*8); }
          __syncthreads();
#pragma unroll
          for (int ks2=0; ks2<2; ++ks2){
#pragma unroll
            for (int nf=0; nf<2; ++nf){
              int n = wv*32 + nf*16 + ln;
              short8 bfr = smB[n*64 + kc*8 + ((ks2*4+lk)^(n&7))];
#pragma unroll
              for (int mf=0; mf<4; ++mf){
                int m = mf*16+ln;
                short8 afr = smAc[m*8 + ((ks2*4+lk)^(m&7))];
                acc[mf][nf] = __builtin_amdgcn_mfma_f32_16x16x32_bf16(afr, bfr, acc[mf][nf], 0,0,0);
              }
            }
          }
        }

        float se[4][4];
#pragma unroll
        for (int mf=0; mf<4; ++mf)
#pragma unroll
          for (int r=0;r<4;++r) se[mf][r] = 0.f;
#pragma unroll
        for (int nf=0; nf<2; ++nf){
          int ng = v0 + wv*32 + nf*16 + ln;
          float bo = b_o[ng];
#pragma unroll
          for (int mf=0; mf<4; ++mf)
#pragma unroll
            for (int r=0;r<4;++r){
              int m = mf*16 + lk*4 + r;
              float lg = acc[mf][nf][r] + bo;
              se[mf][r] += __expf(lg);
              if (ng == tid_s[m]) tgt[td*64 + m] = lg;
            }
        }
#pragma unroll
        for (int off=1; off<16; off<<=1)
#pragma unroll
          for (int mf=0; mf<4; ++mf)
#pragma unroll
            for (int r=0;r<4;++r) se[mf][r] += __shfl_xor(se[mf][r], off);
        if (ln == 0){
#pragma unroll
          for (int mf=0; mf<4; ++mf)
            *(f32x4*)&redf[wv*64 + mf*16 + lk*4] = (f32x4){se[mf][0],se[mf][1],se[mf][2],se[mf][3]};
        }
        __syncthreads();
        if (t < 64){
          float ssum = redf[t] + redf[64+t] + redf[128+t] + redf[192+t];
          partial[(long)vt*3008 + td*64 + t] = ssum;
        }
      }
    }
  }
}

__global__ void ce_combine(const float* __restrict__ partial, const float* __restrict__ tgt,
                           float* __restrict__ ce_row){
  int r = blockIdx.x*256 + threadIdx.x;
  if (r < 3008){
    float s = 0.f;
    for (int i=0;i<250;++i) s += partial[(long)i*3008 + r];
    ce_row[r] = __logf(s) - tgt[r];
  }
}

__global__ void ce_final(const float* __restrict__ ce_row, float* __restrict__ out){
  __shared__ float red[256];
  float s = 0.f;
  for (int i=threadIdx.x; i<3008; i+=256) s += ce_row[i];
  red[threadIdx.x] = s;
  __syncthreads();
  for (int off=128; off>0; off>>=1){
    if (threadIdx.x < off) red[threadIdx.x] += red[threadIdx.x + off];
    __syncthreads();
  }
  if (threadIdx.x == 0) out[0] = red[0] * (1.0f/4096.0f);
}

// ---------------------------------------------------------------------------
extern "C" void kernel_launch(void* const* d_in, const int* in_sizes, int n_in,
                              void* d_out, int out_size, void* d_ws, size_t ws_size,
                              hipStream_t stream)
{
  (void)in_sizes; (void)n_in; (void)out_size; (void)ws_size;
  const float* feat    = (const float*)d_in[0];
  const float* caption = (const float*)d_in[1];
  const int*   ids     = (const int*)d_in[2];
  const float* w_ih1  = (const float*)d_in[3];
  const float* w_hh1  = (const float*)d_in[4];
  const float* b_ih1  = (const float*)d_in[5];
  const float* b_hh1  = (const float*)d_in[6];
  const float* w_ih2  = (const float*)d_in[7];
  const float* w_hh2  = (const float*)d_in[8];
  const float* b_ih2  = (const float*)d_in[9];
  const float* b_hh2  = (const float*)d_in[10];
  const float* w_hhd1 = (const float*)d_in[12];
  const float* b_ihd1 = (const float*)d_in[13];
  const float* b_hhd1 = (const float*)d_in[14];
  const float* w_ihd2 = (const float*)d_in[15];
  const float* w_hhd2 = (const float*)d_in[16];
  const float* b_ihd2 = (const float*)d_in[17];
  const float* b_hhd2 = (const float*)d_in[18];
  const float* w_o    = (const float*)d_in[19];
  const float* b_o    = (const float*)d_in[20];

  char* p = (char*)d_ws;
  unsigned short* h1    = (unsigned short*)p; p += 96L*BH_*2;      // 6.29 MB
  unsigned short* h2    = (unsigned short*)p; p += 96L*BH_*2;      // 6.29 MB
  unsigned short* w1e   = (unsigned short*)p; p += 2048L*512*2;
  unsigned short* w1d   = (unsigned short*)p; p += 2048L*512*2;
  unsigned short* w2e   = (unsigned short*)p; p += 2048L*1024*2;
  unsigned short* w2d   = (unsigned short*)p; p += 2048L*1024*2;
  unsigned short* wx1   = (unsigned short*)p; p += 2048L*512*2;
  unsigned short* wcap  = (unsigned short*)p; p += 2048L*512*2;
  unsigned short* x1b   = (unsigned short*)p; p += 48L*BG_*2;      // 12.6 MB
  unsigned short* capqb = (unsigned short*)p; p += 47L*BG_*2;      // 12.3 MB
  unsigned short* wo_bf = (unsigned short*)p; p += 32000L*512*2;   // 32.8 MB
  float* bd1s  = (float*)p; p += 2048*4;
  float* b2es  = (float*)p; p += 2048*4;
  float* partial = (float*)p; p += 250L*3008*4;                    // 3.0 MB
  float* tgt   = (float*)p; p += 3008*4;
  float* ce_row= (float*)p; p += 3008*4;
  unsigned* flags = (unsigned*)p; p += 4096*4;

  // all conversions + init, one launch
  prep_kernel<<<1024, 256, 0, stream>>>(
      w_hh1, w_hhd1, w_hh2, w_ih2, w_hhd2, w_ihd2, w_ih1, w_o,
      b_ihd1, b_hhd1, b_ih2, b_hh2,
      w1e, w1d, w2e, w2d, wx1, wcap, wo_bf, bd1s, b2es, h1, h2, flags);

  // X1 + capQ, one launch
  mm_pre2_kernel<<<dim3(95,8), 512, 0, stream>>>(
      feat, caption, wx1, wcap, b_ih1, b_hh1, b_ihd2, b_hhd2, x1b, capqb);

  // chain + overlapped CE
  mega_kernel<<<64+NCE_, 256, 0, stream>>>(
      w1e, w1d, w2e, w2d, x1b, capqb, bd1s, b2es, h1, h2,
      wo_bf, b_o, ids, partial, tgt, flags);

  ce_combine<<<12, 256, 0, stream>>>(partial, tgt, ce_row);
  ce_final<<<1, 256, 0, stream>>>(ce_row, (float*)d_out);
}